// Round 6
// baseline (549.209 us; speedup 1.0000x reference)
//
#include <hip/hip_runtime.h>

typedef unsigned short u16;
typedef unsigned int u32;
typedef __attribute__((ext_vector_type(8))) short short8;
typedef __attribute__((ext_vector_type(4))) float f32x4;

#define N_IT 80000
#define SLOT 10240000

__device__ __forceinline__ float wred(float v) {
#pragma unroll
    for (int s = 32; s; s >>= 1) v += __shfl_xor(v, s);
    return v;
}
__device__ __forceinline__ float sigf(float x) { return 1.f / (1.f + expf(-x)); }
__device__ __forceinline__ u16 f2bf(float f) {          // RNE f32->bf16
    u32 x = __float_as_uint(f);
    u32 r = x + 0x7fffu + ((x >> 16) & 1u);
    return (u16)(r >> 16);
}
__device__ __forceinline__ float bf2f(u16 v) {
    return __uint_as_float(((u32)v) << 16);
}
__device__ __forceinline__ f32x4 mfma16(short8 a, short8 b, f32x4 c) {
    return __builtin_amdgcn_mfma_f32_16x16x32_bf16(a, b, c, 0, 0, 0);
}
// xor-swizzle within 32-lane half (BitMode): pattern = (xor<<10)|0x1F
#define SWZ(v, pat) __int_as_float(__builtin_amdgcn_ds_swizzle(__float_as_int(v), pat))
__device__ __forceinline__ float red16(float t) {   // sum over 16-lane group
    t += SWZ(t, 0x041F);
    t += SWZ(t, 0x081F);
    t += SWZ(t, 0x101F);
    t += SWZ(t, 0x201F);
    return t;
}
__device__ __forceinline__ float dot4(float4 a, float4 b) {
    return a.x * b.x + a.y * b.y + a.z * b.z + a.w * b.w;
}

// ---------- weight converts (W_ih 49152 + W1 16384 = 65536 elems) ----------
__global__ __launch_bounds__(256) void k_cvtall(const float* __restrict__ Wih,
                                                const float* __restrict__ W1,
                                                u16* __restrict__ wihbf,
                                                u16* __restrict__ w1bf) {
    int i = blockIdx.x * 256 + threadIdx.x;
    if (i < 49152) {
        wihbf[i] = f2bf(Wih[i]);
    } else {
        int j = i - 49152;
        w1bf[j] = f2bf(W1[j]);
    }
}

// ---------- row L2-normalize (wave per row) ----------
__global__ __launch_bounds__(256) void k_norm(const float* __restrict__ x,
                                              float* __restrict__ xn) {
    int wid = (blockIdx.x * blockDim.x + threadIdx.x) >> 6;
    int l = threadIdx.x & 63;
    size_t base = (size_t)wid * 128;
    float2 v = *(const float2*)(x + base + 2 * l);
    float s = wred(v.x * v.x + v.y * v.y);
    float r = 1.f / sqrtf(s + 1e-12f);
    *(float2*)(xn + base + 2 * l) = make_float2(v.x * r, v.y * r);
}

// ---------- hop-1 routing: 16 lanes/item, 8 dims/lane ----------
// launch_bounds(256,2): z[] (96 VGPR) must stay in registers ((256,3) spilled: 7x slower)
__global__ __launch_bounds__(256, 2) void k_route(const float* __restrict__ xn,
                                                  const int* __restrict__ adj,
                                                  float* __restrict__ out) {
    int tid = blockIdx.x * 256 + threadIdx.x;
    int item = tid >> 4;
    int sl = threadIdx.x & 15;
    const float4* xr = (const float4*)(xn + (size_t)item * 128 + sl * 8);
    float4 x0 = xr[0], x1 = xr[1];
    const int4* ar = (const int4*)(adj + (size_t)(item + 1) * 12);
    int4 a0 = ar[0], a1 = ar[1], a2 = ar[2];
    float4 z0[12], z1[12];
#define LDZ(i, comp)                                                            \
    {                                                                           \
        const float4* zr = (const float4*)(xn + (size_t)((comp) - 1) * 128 + sl * 8); \
        z0[i] = zr[0]; z1[i] = zr[1];                                           \
    }
    LDZ(0, a0.x) LDZ(1, a0.y) LDZ(2, a0.z) LDZ(3, a0.w)
    LDZ(4, a1.x) LDZ(5, a1.y) LDZ(6, a1.z) LDZ(7, a1.w)
    LDZ(8, a2.x) LDZ(9, a2.y) LDZ(10, a2.z) LDZ(11, a2.w)
#undef LDZ
    float4 u0 = x0, u1 = x1;
#pragma unroll
    for (int it = 0; it < 4; it++) {
        float p[12]; float sum = 0.f;
#pragma unroll
        for (int m = 0; m < 12; m++) {
            float t = dot4(u0, z0[m]) + dot4(u1, z1[m]);
            t = red16(t);
            p[m] = __expf(t);           // |t|<=1 (unit vectors): no max-sub needed
            sum += p[m];
        }
        float inv = 1.f / sum;
        u0 = x0; u1 = x1;
#pragma unroll
        for (int m = 0; m < 12; m++) {
            float pm = p[m] * inv;
            u0.x += pm * z0[m].x; u0.y += pm * z0[m].y;
            u0.z += pm * z0[m].z; u0.w += pm * z0[m].w;
            u1.x += pm * z1[m].x; u1.y += pm * z1[m].y;
            u1.z += pm * z1[m].z; u1.w += pm * z1[m].w;
        }
        float nn = red16(dot4(u0, u0) + dot4(u1, u1));
        float rr = 1.f / sqrtf(nn + 1e-12f);
        u0.x *= rr; u0.y *= rr; u0.z *= rr; u0.w *= rr;
        u1.x *= rr; u1.y *= rr; u1.z *= rr; u1.w *= rr;
    }
    float4* orow = (float4*)(out + (size_t)item * 128 + sl * 8);
    orow[0] = u0; orow[1] = u1;
}

// ---------- hop-2 routing FUSED with LN1: emits only ivbf (bf16) ----------
__global__ __launch_bounds__(256, 2) void k_route2ln(const float* __restrict__ xn,
                                                     const float* __restrict__ emb,
                                                     const int* __restrict__ adj,
                                                     const float* __restrict__ g,
                                                     const float* __restrict__ bb,
                                                     u32* __restrict__ ivbf) {
    int tid = blockIdx.x * 256 + threadIdx.x;
    int item = tid >> 4;
    int sl = threadIdx.x & 15;
    const float4* xr = (const float4*)(xn + (size_t)item * 128 + sl * 8);
    float4 x0 = xr[0], x1 = xr[1];
    const int4* ar = (const int4*)(adj + (size_t)(item + 1) * 12);
    int4 a0 = ar[0], a1 = ar[1], a2 = ar[2];
    float4 z0[12], z1[12];
#define LDZ(i, comp)                                                            \
    {                                                                           \
        const float4* zr = (const float4*)(xn + (size_t)((comp) - 1) * 128 + sl * 8); \
        z0[i] = zr[0]; z1[i] = zr[1];                                           \
    }
    LDZ(0, a0.x) LDZ(1, a0.y) LDZ(2, a0.z) LDZ(3, a0.w)
    LDZ(4, a1.x) LDZ(5, a1.y) LDZ(6, a1.z) LDZ(7, a1.w)
    LDZ(8, a2.x) LDZ(9, a2.y) LDZ(10, a2.z) LDZ(11, a2.w)
#undef LDZ
    float4 u0 = x0, u1 = x1;
#pragma unroll
    for (int it = 0; it < 4; it++) {
        float p[12]; float sum = 0.f;
#pragma unroll
        for (int m = 0; m < 12; m++) {
            float t = dot4(u0, z0[m]) + dot4(u1, z1[m]);
            t = red16(t);
            p[m] = __expf(t);
            sum += p[m];
        }
        float inv = 1.f / sum;
        u0 = x0; u1 = x1;
#pragma unroll
        for (int m = 0; m < 12; m++) {
            float pm = p[m] * inv;
            u0.x += pm * z0[m].x; u0.y += pm * z0[m].y;
            u0.z += pm * z0[m].z; u0.w += pm * z0[m].w;
            u1.x += pm * z1[m].x; u1.y += pm * z1[m].y;
            u1.z += pm * z1[m].z; u1.w += pm * z1[m].w;
        }
        float nn = red16(dot4(u0, u0) + dot4(u1, u1));
        float rr = 1.f / sqrtf(nn + 1e-12f);
        u0.x *= rr; u0.y *= rr; u0.z *= rr; u0.w *= rr;
        u1.x *= rr; u1.y *= rr; u1.z *= rr; u1.w *= rr;
    }
    // acc = emb + out1(x) + out2(u);  LN over 128 dims via red16
    const float4* er = (const float4*)(emb + (size_t)item * 128 + sl * 8);
    float4 e0 = er[0], e1 = er[1];
    float v[8];
    v[0] = e0.x + x0.x + u0.x; v[1] = e0.y + x0.y + u0.y;
    v[2] = e0.z + x0.z + u0.z; v[3] = e0.w + x0.w + u0.w;
    v[4] = e1.x + x1.x + u1.x; v[5] = e1.y + x1.y + u1.y;
    v[6] = e1.z + x1.z + u1.z; v[7] = e1.w + x1.w + u1.w;
    float s = 0.f, q = 0.f;
#pragma unroll
    for (int j = 0; j < 8; j++) { s += v[j]; q += v[j] * v[j]; }
    s = red16(s); q = red16(q);
    float mean = s * (1.f / 128.f);
    float var = q * (1.f / 128.f) - mean * mean;
    float r = 1.f / sqrtf(var + 1e-5f);
    const float4* gr = (const float4*)(g + sl * 8);
    const float4* br = (const float4*)(bb + sl * 8);
    float4 g0 = gr[0], g1 = gr[1], bw0 = br[0], bw1 = br[1];
    float y[8];
    y[0] = (v[0] - mean) * r * g0.x + bw0.x; y[1] = (v[1] - mean) * r * g0.y + bw0.y;
    y[2] = (v[2] - mean) * r * g0.z + bw0.z; y[3] = (v[3] - mean) * r * g0.w + bw0.w;
    y[4] = (v[4] - mean) * r * g1.x + bw1.x; y[5] = (v[5] - mean) * r * g1.y + bw1.y;
    y[6] = (v[6] - mean) * r * g1.z + bw1.z; y[7] = (v[7] - mean) * r * g1.w + bw1.w;
    u32 o0 = ((u32)f2bf(y[1]) << 16) | f2bf(y[0]);
    u32 o1 = ((u32)f2bf(y[3]) << 16) | f2bf(y[2]);
    u32 o2 = ((u32)f2bf(y[5]) << 16) | f2bf(y[4]);
    u32 o3 = ((u32)f2bf(y[7]) << 16) | f2bf(y[6]);
    // row stride is 64 u32 (128 bf16). item*32 here was the R4/R5 bug:
    // adjacent items' rows overlapped by half and corrupted ivbf.
    uint4* orow = (uint4*)(ivbf + (size_t)item * 64 + sl * 4);
    *orow = make_uint4(o0, o1, o2, o3);
}

// ---------- h = leaky_relu(iv @ W1^T + b1) via bf16 MFMA ----------
__global__ __launch_bounds__(256) void k_hmf(const u16* __restrict__ ivbf,
                                             const u16* __restrict__ w1bf,
                                             const float* __restrict__ b1,
                                             float* __restrict__ h) {
    int w = threadIdx.x >> 6, l = threadIdx.x & 63;
    int mt = blockIdx.x * 4 + w;
    int row = mt * 16 + (l & 15);
    int ko = (l >> 4) * 8;
    const u16* ap = ivbf + (size_t)row * 128 + ko;
    short8 A[4];
#pragma unroll
    for (int kb = 0; kb < 4; kb++) A[kb] = *(const short8*)(ap + kb * 32);
    int rowb = mt * 16 + (l >> 4) * 4;
    for (int nt = 0; nt < 8; nt++) {
        int col = nt * 16 + (l & 15);
        const u16* wp = w1bf + col * 128 + ko;
        f32x4 acc = {0.f, 0.f, 0.f, 0.f};
#pragma unroll
        for (int kb = 0; kb < 4; kb++)
            acc = mfma16(A[kb], *(const short8*)(wp + kb * 32), acc);
        float bias = b1[col];
#pragma unroll
        for (int q = 0; q < 4; q++) {
            float v = acc[q] + bias;
            h[(size_t)(rowb + q) * 128 + col] = v >= 0.f ? v : 0.01f * v;
        }
    }
}

// ---------- pop logits -> softmax -> @anchors_emb -> LN2 -> pv (bf16) ----------
__global__ __launch_bounds__(1024) void k_pop2(const float* __restrict__ h,
                                               const u16* __restrict__ ivbf,
                                               const float* __restrict__ W2,
                                               const float* __restrict__ b2,
                                               const float* __restrict__ tau,
                                               const int* __restrict__ anchors,
                                               const float* __restrict__ g2,
                                               const float* __restrict__ bb2,
                                               u32* __restrict__ pvbf) {
    __shared__ float W2T[128][20];
    __shared__ __align__(8) float anch[20][128];
    __shared__ __align__(8) float hst[16][128];
    __shared__ float lst[16][20];
    int tid = threadIdx.x;
    for (int e = tid; e < 20 * 128; e += 1024) {
        int k = e >> 7, d = e & 127;
        W2T[d][k] = W2[e];
        anch[k][d] = bf2f(ivbf[(size_t)(anchors[k] - 1) * 128 + d]);
    }
    __syncthreads();
    int w = tid >> 6, l = tid & 63;
    int item = blockIdx.x * 16 + w;
    const float* hr = h + (size_t)item * 128;
    float2 hv = *(const float2*)(hr + 2 * l);
    *(float2*)&hst[w][2 * l] = hv;
    if (l < 20) {
        float acc = b2[l];
        for (int j = 0; j < 128; j++) acc += hst[w][j] * W2T[j][l];
        lst[w][l] = acc / tau[0];
    }
    float p[20]; float mx = -1e30f;
#pragma unroll
    for (int k = 0; k < 20; k++) { p[k] = lst[w][k]; mx = fmaxf(mx, p[k]); }
    float sum = 0.f;
#pragma unroll
    for (int k = 0; k < 20; k++) { p[k] = expf(p[k] - mx); sum += p[k]; }
    float inv = 1.f / sum;
    float o0 = 0.f, o1 = 0.f;
#pragma unroll
    for (int k = 0; k < 20; k++) {
        float pk = p[k] * inv;
        float2 av = *(const float2*)&anch[k][2 * l];
        o0 += pk * av.x; o1 += pk * av.y;
    }
    float s = wred(o0 + o1), q = wred(o0 * o0 + o1 * o1);
    float mean = s * (1.f / 128.f);
    float var = q * (1.f / 128.f) - mean * mean;
    float rr = 1.f / sqrtf(var + 1e-5f);
    float2 gg = *(const float2*)(g2 + 2 * l);
    float2 bg = *(const float2*)(bb2 + 2 * l);
    float y0 = (o0 - mean) * rr * gg.x + bg.x;
    float y1 = (o1 - mean) * rr * gg.y + bg.y;
    pvbf[(size_t)item * 64 + l] = ((u32)f2bf(y1) << 16) | f2bf(y0);
}

// ---------- gi_all[512*50][384] = gather(iv/pv)[sess] @ W_ih^T + b_ih ----------
__global__ __launch_bounds__(256) void k_gi(const int* __restrict__ sess,
                                            const u16* __restrict__ ivbf,
                                            const u16* __restrict__ pvbf,
                                            const u16* __restrict__ wbf,
                                            const float* __restrict__ bih,
                                            float* __restrict__ gi) {
    int w = threadIdx.x >> 6, l = threadIdx.x & 63;
    int mt = blockIdx.x * 4 + w;
    int r = mt * 16 + (l & 15);
    int s = r / 50, t = r - s * 50;
    int idx = sess[(s & 255) * 50 + t];
    const u16* srcb = (s < 256) ? ivbf : pvbf;
    int ko = (l >> 4) * 8;
    const short8 Z8 = {0, 0, 0, 0, 0, 0, 0, 0};
    short8 A[4];
    if (idx == 0) {
#pragma unroll
        for (int kb = 0; kb < 4; kb++) A[kb] = Z8;
    } else {
        const u16* rp = srcb + (size_t)(idx - 1) * 128 + ko;
#pragma unroll
        for (int kb = 0; kb < 4; kb++) A[kb] = *(const short8*)(rp + kb * 32);
    }
    int rowb = mt * 16 + (l >> 4) * 4;
    for (int nt = 0; nt < 24; nt++) {
        int gcol = nt * 16 + (l & 15);
        const u16* wp = wbf + gcol * 128 + ko;
        f32x4 acc = {0.f, 0.f, 0.f, 0.f};
#pragma unroll
        for (int kb = 0; kb < 4; kb++)
            acc = mfma16(A[kb], *(const short8*)(wp + kb * 32), acc);
        float bias = bih[gcol];
#pragma unroll
        for (int q = 0; q < 4; q++)
            gi[(size_t)(rowb + q) * 384 + gcol] = acc[q] + bias;
    }
}

// ---------- GRU: one sequence per block (512 blocks), W_hh rows in VGPRs ----------
__global__ __launch_bounds__(384, 2) void k_gru(const float* __restrict__ gi,
                                                const float* __restrict__ whh,
                                                const float* __restrict__ bhh,
                                                const int* __restrict__ lengths,
                                                const float* __restrict__ g3,
                                                const float* __restrict__ b3,
                                                const float* __restrict__ g4,
                                                const float* __restrict__ b4,
                                                u32* __restrict__ htbf) {
    __shared__ __align__(16) float hS[2][128];
    __shared__ float rS[128], zS[128], hnS[128], inS[128];
    int g = threadIdx.x, b = blockIdx.x;
    float4 wv[32];
    const float4* wr = (const float4*)(whh + g * 128);
#pragma unroll
    for (int k = 0; k < 32; k++) wv[k] = wr[k];
    float bh = bhh[g];
    if (g < 128) hS[0][g] = 0.f;
    int len = lengths[b & 255];
    const float* giS = gi + (size_t)b * 50 * 384 + g;
    __syncthreads();
    int par = 0;
    for (int t = 0; t < len; t++) {
        float ga = giS[t * 384];
        float aA = bh;
#pragma unroll
        for (int k = 0; k < 32; k++) {
            float4 w4 = wv[k];
            float4 ha = *(const float4*)&hS[par][k * 4];
            aA += w4.x * ha.x + w4.y * ha.y + w4.z * ha.z + w4.w * ha.w;
        }
        if (g < 128) {
            rS[g] = sigf(ga + aA);
        } else if (g < 256) {
            zS[g - 128] = sigf(ga + aA);
        } else {
            inS[g - 256] = ga; hnS[g - 256] = aA;
        }
        __syncthreads();
        if (g < 128) {
            float n = tanhf(inS[g] + rS[g] * hnS[g]);
            hS[par ^ 1][g] = (1.f - zS[g]) * n + zS[g] * hS[par][g];
        }
        __syncthreads();
        par ^= 1;
    }
    if (g < 64) {
        const float* lg = (b < 256) ? g3 : g4;
        const float* lb = (b < 256) ? b3 : b4;
        float2 v = *(const float2*)&hS[par][2 * g];
        float s = wred(v.x + v.y), q = wred(v.x * v.x + v.y * v.y);
        float mean = s * (1.f / 128.f), var = q * (1.f / 128.f) - mean * mean;
        float r = 1.f / sqrtf(var + 1e-5f);
        float2 gg = *(const float2*)(lg + 2 * g), bg = *(const float2*)(lb + 2 * g);
        float y0 = (v.x - mean) * r * gg.x + bg.x;
        float y1 = (v.y - mean) * r * gg.y + bg.y;
        htbf[(size_t)b * 64 + g] = ((u32)f2bf(y1) << 16) | f2bf(y0);
    }
}

// ---------- scores: BM=256(all) x BN=64/block, bf16 MFMA, 3 outputs ----------
__global__ __launch_bounds__(256) void k_scores(const u16* __restrict__ htbf,
                                                const u16* __restrict__ ivbf,
                                                const u16* __restrict__ pvbf,
                                                const float* __restrict__ a1,
                                                const float* __restrict__ a2,
                                                float* __restrict__ out) {
    int w = threadIdx.x >> 6, l = threadIdx.x & 63;
    int n0 = blockIdx.x * 64;
    int ko = (l >> 4) * 8;
    short8 Ai[4][4], Ap[4][4];
#pragma unroll
    for (int mi = 0; mi < 4; mi++) {
        int row = w * 64 + mi * 16 + (l & 15);
        const u16* pi = htbf + row * 128 + ko;
        const u16* pp = htbf + (row + 256) * 128 + ko;
#pragma unroll
        for (int kb = 0; kb < 4; kb++) {
            Ai[mi][kb] = *(const short8*)(pi + kb * 32);
            Ap[mi][kb] = *(const short8*)(pp + kb * 32);
        }
    }
    float s1 = sigf(a1[0]), s2 = sigf(a2[0]);
    float* sc = out;
    float* si = out + (size_t)20480000;
    float* sp = out + (size_t)40960000;
    for (int nt = 0; nt < 4; nt++) {
        int col = n0 + nt * 16 + (l & 15);
        const u16* bi = ivbf + (size_t)col * 128 + ko;
        const u16* bp = pvbf + (size_t)col * 128 + ko;
        short8 Bi[4], Bp[4];
#pragma unroll
        for (int kb = 0; kb < 4; kb++) {
            Bi[kb] = *(const short8*)(bi + kb * 32);
            Bp[kb] = *(const short8*)(bp + kb * 32);
        }
#pragma unroll
        for (int mi = 0; mi < 4; mi++) {
            f32x4 ai = {0.f, 0.f, 0.f, 0.f}, ap = {0.f, 0.f, 0.f, 0.f};
#pragma unroll
            for (int kb = 0; kb < 4; kb++) {
                ai = mfma16(Ai[mi][kb], Bi[kb], ai);
                ap = mfma16(Ap[mi][kb], Bp[kb], ap);
            }
            int rowb = w * 64 + mi * 16 + (l >> 4) * 4;
#pragma unroll
            for (int q = 0; q < 4; q++) {
                size_t o = (size_t)(rowb + q) * 80000 + col;
                float vi = ai[q], vp = ap[q];
                si[o] = vi;
                sp[o] = vp;
                sc[o] = s1 * vi + s2 * vp;
            }
        }
    }
}

extern "C" void kernel_launch(void* const* d_in, const int* in_sizes, int n_in,
                              void* d_out, int out_size, void* d_ws, size_t ws_size,
                              hipStream_t stream) {
    (void)in_sizes; (void)n_in; (void)out_size; (void)ws_size;
    const int*   sess    = (const int*)d_in[0];
    const int*   lengths = (const int*)d_in[1];
    const float* tau     = (const float*)d_in[4];
    const int*   adj     = (const int*)d_in[5];
    const int*   anchors = (const int*)d_in[6];
    const float* emb     = (const float*)d_in[7];
    const float* W_ih    = (const float*)d_in[8];
    const float* W_hh    = (const float*)d_in[9];
    const float* b_ih    = (const float*)d_in[10];
    const float* b_hh    = (const float*)d_in[11];
    const float* W1      = (const float*)d_in[12];
    const float* b1      = (const float*)d_in[13];
    const float* W2      = (const float*)d_in[14];
    const float* b2      = (const float*)d_in[15];
    const float* a1      = (const float*)d_in[16];
    const float* a2      = (const float*)d_in[17];
    const float* ln1g = (const float*)d_in[18];
    const float* ln1b = (const float*)d_in[19];
    const float* ln2g = (const float*)d_in[20];
    const float* ln2b = (const float*)d_in[21];
    const float* ln3g = (const float*)d_in[22];
    const float* ln3b = (const float*)d_in[23];
    const float* ln4g = (const float*)d_in[24];
    const float* ln4b = (const float*)d_in[25];

    float* out = (float*)d_out;
    // d_out doubles as scratch; all scratch dead before k_scores overwrites it.
    float* o_xn = out;               // normalized emb
    float* o_o1 = out + SLOT;        // hop-1 output
    float* o_gi = out + 2 * SLOT;    // gi_all (512*50*384 = 9.83M floats)
    float* o_h  = out + 3 * SLOT;    // h (MLP output, 10.24M floats)

    u16* ws16   = (u16*)d_ws;        // ~41.2 MB
    u16* ivbf   = ws16;                      // 10,240,000
    u16* pvbf   = ws16 + 10240000;           // 10,240,000
    u16* wihbf  = ws16 + 20480000;           // 49,152
    u16* htbf   = ws16 + 20529152;           // 65,536
    u16* w1bf   = ws16 + 20594688;           // 16,384

    k_cvtall<<<256, 256, 0, stream>>>(W_ih, W1, wihbf, w1bf);
    k_norm<<<20000, 256, 0, stream>>>(emb + 128, o_xn);
    k_route<<<5000, 256, 0, stream>>>(o_xn, adj, o_o1);
    k_route2ln<<<5000, 256, 0, stream>>>(o_o1, emb + 128, adj, ln1g, ln1b, (u32*)ivbf);
    k_hmf<<<1250, 256, 0, stream>>>(ivbf, w1bf, b1, o_h);
    k_pop2<<<5000, 1024, 0, stream>>>(o_h, ivbf, W2, b2, tau, anchors, ln2g, ln2b,
                                      (u32*)pvbf);
    k_gi<<<400, 256, 0, stream>>>(sess, ivbf, pvbf, wihbf, b_ih, o_gi);
    k_gru<<<512, 384, 0, stream>>>(o_gi, W_hh, b_hh, lengths, ln3g, ln3b, ln4g, ln4b,
                                   (u32*)htbf);
    k_scores<<<1250, 256, 0, stream>>>(htbf, ivbf, pvbf, a1, a2, out);
}

// Round 7
// 429.070 us; speedup vs baseline: 1.2800x; 1.2800x over previous
//
#include <hip/hip_runtime.h>

typedef unsigned short u16;
typedef unsigned int u32;
typedef __attribute__((ext_vector_type(8))) short short8;
typedef __attribute__((ext_vector_type(4))) float f32x4;

#define N_IT 80000
#define SLOT 10240000

__device__ __forceinline__ float wred(float v) {
#pragma unroll
    for (int s = 32; s; s >>= 1) v += __shfl_xor(v, s);
    return v;
}
__device__ __forceinline__ float sigf(float x) { return 1.f / (1.f + expf(-x)); }
__device__ __forceinline__ u16 f2bf(float f) {          // RNE f32->bf16
    u32 x = __float_as_uint(f);
    u32 r = x + 0x7fffu + ((x >> 16) & 1u);
    return (u16)(r >> 16);
}
__device__ __forceinline__ float bf2f(u16 v) {
    return __uint_as_float(((u32)v) << 16);
}
__device__ __forceinline__ u32 pack2(float lo, float hi) {
    return ((u32)f2bf(hi) << 16) | f2bf(lo);
}
__device__ __forceinline__ f32x4 mfma16(short8 a, short8 b, f32x4 c) {
    return __builtin_amdgcn_mfma_f32_16x16x32_bf16(a, b, c, 0, 0, 0);
}
// xor-swizzle within 32-lane half (BitMode): pattern = (xor<<10)|0x1F
#define SWZ(v, pat) __int_as_float(__builtin_amdgcn_ds_swizzle(__float_as_int(v), pat))
__device__ __forceinline__ float red16(float t) {   // sum over 16-lane group
    t += SWZ(t, 0x041F);
    t += SWZ(t, 0x081F);
    t += SWZ(t, 0x101F);
    t += SWZ(t, 0x201F);
    return t;
}
__device__ __forceinline__ float red16max(float t) { // max over 16-lane group
    t = fmaxf(t, SWZ(t, 0x041F));
    t = fmaxf(t, SWZ(t, 0x081F));
    t = fmaxf(t, SWZ(t, 0x101F));
    t = fmaxf(t, SWZ(t, 0x201F));
    return t;
}
__device__ __forceinline__ float dot4(float4 a, float4 b) {
    return a.x * b.x + a.y * b.y + a.z * b.z + a.w * b.w;
}
// unpack uint4 (8 packed bf16) -> two float4
__device__ __forceinline__ void unp8(uint4 w, float4& a, float4& b) {
    a.x = __uint_as_float(w.x << 16); a.y = __uint_as_float(w.x & 0xFFFF0000u);
    a.z = __uint_as_float(w.y << 16); a.w = __uint_as_float(w.y & 0xFFFF0000u);
    b.x = __uint_as_float(w.z << 16); b.y = __uint_as_float(w.z & 0xFFFF0000u);
    b.z = __uint_as_float(w.w << 16); b.w = __uint_as_float(w.w & 0xFFFF0000u);
}

// ---------- weight converts: W_ih, W1, W2 (padded [32][128]) ----------
__global__ __launch_bounds__(256) void k_cvtall(const float* __restrict__ Wih,
                                                const float* __restrict__ W1,
                                                const float* __restrict__ W2,
                                                u16* __restrict__ wihbf,
                                                u16* __restrict__ w1bf,
                                                u16* __restrict__ w2bf) {
    int i = blockIdx.x * 256 + threadIdx.x;
    if (i < 49152) {
        wihbf[i] = f2bf(Wih[i]);
    } else if (i < 65536) {
        int j = i - 49152;
        w1bf[j] = f2bf(W1[j]);
    } else if (i < 69632) {
        int j = i - 65536;              // w2bf [32][128], rows>=20 zero
        int row = j >> 7, col = j & 127;
        w2bf[j] = (row < 20) ? f2bf(W2[row * 128 + col]) : (u16)0;
    }
}

// ---------- anchors gather + transpose: anchT[128][32] bf16 ----------
__global__ __launch_bounds__(256) void k_prep(const int* __restrict__ anchors,
                                              const u16* __restrict__ ivbf,
                                              u16* __restrict__ anchT) {
    for (int e = threadIdx.x; e < 4096; e += 256) {
        int d = e >> 5, k = e & 31;
        anchT[e] = (k < 20) ? ivbf[(size_t)(anchors[k] - 1) * 128 + d] : (u16)0;
    }
}

// ---------- row L2-normalize -> packed bf16 (wave per row) ----------
__global__ __launch_bounds__(256) void k_normb(const float* __restrict__ x,
                                               u32* __restrict__ xn) {
    int wid = (blockIdx.x * blockDim.x + threadIdx.x) >> 6;
    int l = threadIdx.x & 63;
    size_t base = (size_t)wid * 128;
    float2 v = *(const float2*)(x + base + 2 * l);
    float s = wred(v.x * v.x + v.y * v.y);
    float r = 1.f / sqrtf(s + 1e-12f);
    xn[(size_t)wid * 64 + l] = pack2(v.x * r, v.y * r);
}

// ---------- hop-1 routing on bf16 table: 16 lanes/item, 8 dims/lane ----------
// (256,2): z[] (96 VGPR f32) must stay in registers ((256,3) spilled: 7x slower)
__global__ __launch_bounds__(256, 2) void k_routeb(const u32* __restrict__ xn,
                                                   const int* __restrict__ adj,
                                                   u32* __restrict__ out) {
    int tid = blockIdx.x * 256 + threadIdx.x;
    int item = tid >> 4;
    int sl = threadIdx.x & 15;
    float4 x0, x1;
    unp8(*(const uint4*)(xn + (size_t)item * 64 + sl * 4), x0, x1);
    const int4* ar = (const int4*)(adj + (size_t)(item + 1) * 12);
    int4 a0 = ar[0], a1 = ar[1], a2 = ar[2];
    float4 z0[12], z1[12];
#define LDZ(i, comp)                                                              \
    unp8(*(const uint4*)(xn + (size_t)((comp) - 1) * 64 + sl * 4), z0[i], z1[i]);
    LDZ(0, a0.x) LDZ(1, a0.y) LDZ(2, a0.z) LDZ(3, a0.w)
    LDZ(4, a1.x) LDZ(5, a1.y) LDZ(6, a1.z) LDZ(7, a1.w)
    LDZ(8, a2.x) LDZ(9, a2.y) LDZ(10, a2.z) LDZ(11, a2.w)
#undef LDZ
    float4 u0 = x0, u1 = x1;
#pragma unroll
    for (int it = 0; it < 4; it++) {
        float p[12]; float sum = 0.f;
#pragma unroll
        for (int m = 0; m < 12; m++) {
            float t = dot4(u0, z0[m]) + dot4(u1, z1[m]);
            t = red16(t);
            p[m] = __expf(t);           // |t|<=1 (unit vectors): no max-sub needed
            sum += p[m];
        }
        float inv = 1.f / sum;
        u0 = x0; u1 = x1;
#pragma unroll
        for (int m = 0; m < 12; m++) {
            float pm = p[m] * inv;
            u0.x += pm * z0[m].x; u0.y += pm * z0[m].y;
            u0.z += pm * z0[m].z; u0.w += pm * z0[m].w;
            u1.x += pm * z1[m].x; u1.y += pm * z1[m].y;
            u1.z += pm * z1[m].z; u1.w += pm * z1[m].w;
        }
        float nn = red16(dot4(u0, u0) + dot4(u1, u1));
        float rr = 1.f / sqrtf(nn + 1e-12f);
        u0.x *= rr; u0.y *= rr; u0.z *= rr; u0.w *= rr;
        u1.x *= rr; u1.y *= rr; u1.z *= rr; u1.w *= rr;
    }
    uint4 o = make_uint4(pack2(u0.x, u0.y), pack2(u0.z, u0.w),
                         pack2(u1.x, u1.y), pack2(u1.z, u1.w));
    *(uint4*)(out + (size_t)item * 64 + sl * 4) = o;
}

// ---------- hop-2 routing (bf16 table) FUSED with LN1 -> ivbf ----------
__global__ __launch_bounds__(256, 2) void k_route2lnb(const u32* __restrict__ xn,
                                                      const float* __restrict__ emb,
                                                      const int* __restrict__ adj,
                                                      const float* __restrict__ g,
                                                      const float* __restrict__ bb,
                                                      u32* __restrict__ ivbf) {
    int tid = blockIdx.x * 256 + threadIdx.x;
    int item = tid >> 4;
    int sl = threadIdx.x & 15;
    float4 x0, x1;
    unp8(*(const uint4*)(xn + (size_t)item * 64 + sl * 4), x0, x1);
    const int4* ar = (const int4*)(adj + (size_t)(item + 1) * 12);
    int4 a0 = ar[0], a1 = ar[1], a2 = ar[2];
    float4 z0[12], z1[12];
#define LDZ(i, comp)                                                              \
    unp8(*(const uint4*)(xn + (size_t)((comp) - 1) * 64 + sl * 4), z0[i], z1[i]);
    LDZ(0, a0.x) LDZ(1, a0.y) LDZ(2, a0.z) LDZ(3, a0.w)
    LDZ(4, a1.x) LDZ(5, a1.y) LDZ(6, a1.z) LDZ(7, a1.w)
    LDZ(8, a2.x) LDZ(9, a2.y) LDZ(10, a2.z) LDZ(11, a2.w)
#undef LDZ
    float4 u0 = x0, u1 = x1;
#pragma unroll
    for (int it = 0; it < 4; it++) {
        float p[12]; float sum = 0.f;
#pragma unroll
        for (int m = 0; m < 12; m++) {
            float t = dot4(u0, z0[m]) + dot4(u1, z1[m]);
            t = red16(t);
            p[m] = __expf(t);
            sum += p[m];
        }
        float inv = 1.f / sum;
        u0 = x0; u1 = x1;
#pragma unroll
        for (int m = 0; m < 12; m++) {
            float pm = p[m] * inv;
            u0.x += pm * z0[m].x; u0.y += pm * z0[m].y;
            u0.z += pm * z0[m].z; u0.w += pm * z0[m].w;
            u1.x += pm * z1[m].x; u1.y += pm * z1[m].y;
            u1.z += pm * z1[m].z; u1.w += pm * z1[m].w;
        }
        float nn = red16(dot4(u0, u0) + dot4(u1, u1));
        float rr = 1.f / sqrtf(nn + 1e-12f);
        u0.x *= rr; u0.y *= rr; u0.z *= rr; u0.w *= rr;
        u1.x *= rr; u1.y *= rr; u1.z *= rr; u1.w *= rr;
    }
    // acc = emb + out1(x) + out2(u);  LN over 128 dims via red16
    const float4* er = (const float4*)(emb + (size_t)item * 128 + sl * 8);
    float4 e0 = er[0], e1 = er[1];
    float v[8];
    v[0] = e0.x + x0.x + u0.x; v[1] = e0.y + x0.y + u0.y;
    v[2] = e0.z + x0.z + u0.z; v[3] = e0.w + x0.w + u0.w;
    v[4] = e1.x + x1.x + u1.x; v[5] = e1.y + x1.y + u1.y;
    v[6] = e1.z + x1.z + u1.z; v[7] = e1.w + x1.w + u1.w;
    float s = 0.f, q = 0.f;
#pragma unroll
    for (int j = 0; j < 8; j++) { s += v[j]; q += v[j] * v[j]; }
    s = red16(s); q = red16(q);
    float mean = s * (1.f / 128.f);
    float var = q * (1.f / 128.f) - mean * mean;
    float r = 1.f / sqrtf(var + 1e-5f);
    const float4* gr = (const float4*)(g + sl * 8);
    const float4* br = (const float4*)(bb + sl * 8);
    float4 g0 = gr[0], g1 = gr[1], bw0 = br[0], bw1 = br[1];
    float y[8];
    y[0] = (v[0] - mean) * r * g0.x + bw0.x; y[1] = (v[1] - mean) * r * g0.y + bw0.y;
    y[2] = (v[2] - mean) * r * g0.z + bw0.z; y[3] = (v[3] - mean) * r * g0.w + bw0.w;
    y[4] = (v[4] - mean) * r * g1.x + bw1.x; y[5] = (v[5] - mean) * r * g1.y + bw1.y;
    y[6] = (v[6] - mean) * r * g1.z + bw1.z; y[7] = (v[7] - mean) * r * g1.w + bw1.w;
    // row stride = 64 u32 (128 bf16) -- item*32 was the R4/R5 corruption bug
    uint4 o = make_uint4(pack2(y[0], y[1]), pack2(y[2], y[3]),
                         pack2(y[4], y[5]), pack2(y[6], y[7]));
    *(uint4*)(ivbf + (size_t)item * 64 + sl * 4) = o;
}

// ---------- fused MLP -> pop softmax -> @anchors -> LN2 -> pvbf ----------
// 4 waves/block, 16 items/wave, wave-local LDS transposes, no barriers.
__global__ __launch_bounds__(256, 2) void k_popm(const u16* __restrict__ ivbf,
                                                 const u16* __restrict__ w1bf,
                                                 const float* __restrict__ b1,
                                                 const u16* __restrict__ w2bf,
                                                 const float* __restrict__ b2,
                                                 const float* __restrict__ tau,
                                                 const u16* __restrict__ anchT,
                                                 const float* __restrict__ g2,
                                                 const float* __restrict__ bb2,
                                                 u16* __restrict__ pvbf) {
    __shared__ u16 buf[4][16][136];          // per-wave scratch (h / P overlay)
    int w = threadIdx.x >> 6, l = threadIdx.x & 63;
    int g16 = l >> 4, c = l & 15;
    int item0 = blockIdx.x * 64 + w * 16;
    const u16* ap = ivbf + (size_t)(item0 + c) * 128 + g16 * 8;
    short8 A[4];
#pragma unroll
    for (int kb = 0; kb < 4; kb++) A[kb] = *(const short8*)(ap + kb * 32);
    // stage 1: h = leaky(iv @ W1^T + b1), bf16, transposed into LDS
#pragma unroll
    for (int nt = 0; nt < 8; nt++) {
        const u16* wp = w1bf + (nt * 16 + c) * 128 + g16 * 8;
        f32x4 acc = {0.f, 0.f, 0.f, 0.f};
#pragma unroll
        for (int kb = 0; kb < 4; kb++)
            acc = mfma16(A[kb], *(const short8*)(wp + kb * 32), acc);
        float bias = b1[nt * 16 + c];
#pragma unroll
        for (int qq = 0; qq < 4; qq++) {
            float hv = acc[qq] + bias;
            hv = hv >= 0.f ? hv : 0.01f * hv;
            buf[w][4 * g16 + qq][nt * 16 + c] = f2bf(hv);
        }
    }
    // stage 2: logits = h @ W2^T (padded 32); softmax over classes
    short8 A2[4];
#pragma unroll
    for (int kb = 0; kb < 4; kb++)
        A2[kb] = *(const short8*)&buf[w][c][g16 * 8 + kb * 32];
    f32x4 L0 = {0.f, 0.f, 0.f, 0.f}, L1 = {0.f, 0.f, 0.f, 0.f};
#pragma unroll
    for (int kb = 0; kb < 4; kb++) {
        L0 = mfma16(A2[kb], *(const short8*)(w2bf + c * 128 + g16 * 8 + kb * 32), L0);
        L1 = mfma16(A2[kb], *(const short8*)(w2bf + (16 + c) * 128 + g16 * 8 + kb * 32), L1);
    }
    float it = 1.f / tau[0];
    float b2v0 = b2[c];
    float b2v1 = (c < 4) ? b2[16 + c] : 0.f;
#pragma unroll
    for (int qq = 0; qq < 4; qq++) {
        float v0 = (L0[qq] + b2v0) * it;
        float v1 = (c < 4) ? (L1[qq] + b2v1) * it : -1e30f;
        float mx = red16max(fmaxf(v0, v1));
        float e0 = __expf(v0 - mx);
        float e1 = (c < 4) ? __expf(v1 - mx) : 0.f;
        float ssum = red16(e0 + e1);
        float inv = 1.f / ssum;
        buf[w][4 * g16 + qq][c] = f2bf(e0 * inv);
        buf[w][4 * g16 + qq][16 + c] = f2bf(e1 * inv);
    }
    // stage 3: pv = P @ anchors_emb (anchT[128][32]), then LN2
    short8 A3 = *(const short8*)&buf[w][c][g16 * 8];
    f32x4 pv[8];
#pragma unroll
    for (int nt = 0; nt < 8; nt++) {
        const short8 B3 = *(const short8*)(anchT + (nt * 16 + c) * 32 + g16 * 8);
        f32x4 zz = {0.f, 0.f, 0.f, 0.f};
        pv[nt] = mfma16(A3, B3, zz);
    }
    float g2v[8], b2gv[8];
#pragma unroll
    for (int t = 0; t < 8; t++) { g2v[t] = g2[t * 16 + c]; b2gv[t] = bb2[t * 16 + c]; }
#pragma unroll
    for (int qq = 0; qq < 4; qq++) {
        float ps = 0.f, psq = 0.f;
#pragma unroll
        for (int t = 0; t < 8; t++) { float x = pv[t][qq]; ps += x; psq += x * x; }
        float s = red16(ps), sq = red16(psq);
        float mean = s * (1.f / 128.f);
        float var = sq * (1.f / 128.f) - mean * mean;
        float r = 1.f / sqrtf(var + 1e-5f);
        size_t base = (size_t)(item0 + 4 * g16 + qq) * 128;
#pragma unroll
        for (int t = 0; t < 8; t++) {
            float y = (pv[t][qq] - mean) * r * g2v[t] + b2gv[t];
            pvbf[base + t * 16 + c] = f2bf(y);
        }
    }
}

// ---------- gi_all[512*50][384] = gather(iv/pv)[sess] @ W_ih^T + b_ih ----------
__global__ __launch_bounds__(256) void k_gi(const int* __restrict__ sess,
                                            const u16* __restrict__ ivbf,
                                            const u16* __restrict__ pvbf,
                                            const u16* __restrict__ wbf,
                                            const float* __restrict__ bih,
                                            float* __restrict__ gi) {
    int w = threadIdx.x >> 6, l = threadIdx.x & 63;
    int mt = blockIdx.x * 4 + w;
    int r = mt * 16 + (l & 15);
    int s = r / 50, t = r - s * 50;
    int idx = sess[(s & 255) * 50 + t];
    const u16* srcb = (s < 256) ? ivbf : pvbf;
    int ko = (l >> 4) * 8;
    const short8 Z8 = {0, 0, 0, 0, 0, 0, 0, 0};
    short8 A[4];
    if (idx == 0) {
#pragma unroll
        for (int kb = 0; kb < 4; kb++) A[kb] = Z8;
    } else {
        const u16* rp = srcb + (size_t)(idx - 1) * 128 + ko;
#pragma unroll
        for (int kb = 0; kb < 4; kb++) A[kb] = *(const short8*)(rp + kb * 32);
    }
    int rowb = mt * 16 + (l >> 4) * 4;
    for (int nt = 0; nt < 24; nt++) {
        int gcol = nt * 16 + (l & 15);
        const u16* wp = wbf + gcol * 128 + ko;
        f32x4 acc = {0.f, 0.f, 0.f, 0.f};
#pragma unroll
        for (int kb = 0; kb < 4; kb++)
            acc = mfma16(A[kb], *(const short8*)(wp + kb * 32), acc);
        float bias = bih[gcol];
#pragma unroll
        for (int q = 0; q < 4; q++)
            gi[(size_t)(rowb + q) * 384 + gcol] = acc[q] + bias;
    }
}

// ---------- GRU: one sequence per block (512 blocks), W_hh rows in VGPRs ----------
__global__ __launch_bounds__(384, 2) void k_gru(const float* __restrict__ gi,
                                                const float* __restrict__ whh,
                                                const float* __restrict__ bhh,
                                                const int* __restrict__ lengths,
                                                const float* __restrict__ g3,
                                                const float* __restrict__ b3,
                                                const float* __restrict__ g4,
                                                const float* __restrict__ b4,
                                                u32* __restrict__ htbf) {
    __shared__ __align__(16) float hS[2][128];
    __shared__ float rS[128], zS[128], hnS[128], inS[128];
    int g = threadIdx.x, b = blockIdx.x;
    float4 wv[32];
    const float4* wr = (const float4*)(whh + g * 128);
#pragma unroll
    for (int k = 0; k < 32; k++) wv[k] = wr[k];
    float bh = bhh[g];
    if (g < 128) hS[0][g] = 0.f;
    int len = lengths[b & 255];
    const float* giS = gi + (size_t)b * 50 * 384 + g;
    __syncthreads();
    int par = 0;
    for (int t = 0; t < len; t++) {
        float ga = giS[t * 384];
        float aA = bh;
#pragma unroll
        for (int k = 0; k < 32; k++) {
            float4 w4 = wv[k];
            float4 ha = *(const float4*)&hS[par][k * 4];
            aA += w4.x * ha.x + w4.y * ha.y + w4.z * ha.z + w4.w * ha.w;
        }
        if (g < 128) {
            rS[g] = sigf(ga + aA);
        } else if (g < 256) {
            zS[g - 128] = sigf(ga + aA);
        } else {
            inS[g - 256] = ga; hnS[g - 256] = aA;
        }
        __syncthreads();
        if (g < 128) {
            float n = tanhf(inS[g] + rS[g] * hnS[g]);
            hS[par ^ 1][g] = (1.f - zS[g]) * n + zS[g] * hS[par][g];
        }
        __syncthreads();
        par ^= 1;
    }
    if (g < 64) {
        const float* lg = (b < 256) ? g3 : g4;
        const float* lb = (b < 256) ? b3 : b4;
        float2 v = *(const float2*)&hS[par][2 * g];
        float s = wred(v.x + v.y), q = wred(v.x * v.x + v.y * v.y);
        float mean = s * (1.f / 128.f), var = q * (1.f / 128.f) - mean * mean;
        float r = 1.f / sqrtf(var + 1e-5f);
        float2 gg = *(const float2*)(lg + 2 * g), bg = *(const float2*)(lb + 2 * g);
        float y0 = (v.x - mean) * r * gg.x + bg.x;
        float y1 = (v.y - mean) * r * gg.y + bg.y;
        htbf[(size_t)b * 64 + g] = ((u32)f2bf(y1) << 16) | f2bf(y0);
    }
}

// ---------- scores: BM=256(all) x BN=64/block, bf16 MFMA, 3 outputs ----------
__global__ __launch_bounds__(256) void k_scores(const u16* __restrict__ htbf,
                                                const u16* __restrict__ ivbf,
                                                const u16* __restrict__ pvbf,
                                                const float* __restrict__ a1,
                                                const float* __restrict__ a2,
                                                float* __restrict__ out) {
    int w = threadIdx.x >> 6, l = threadIdx.x & 63;
    int n0 = blockIdx.x * 64;
    int ko = (l >> 4) * 8;
    short8 Ai[4][4], Ap[4][4];
#pragma unroll
    for (int mi = 0; mi < 4; mi++) {
        int row = w * 64 + mi * 16 + (l & 15);
        const u16* pi = htbf + row * 128 + ko;
        const u16* pp = htbf + (row + 256) * 128 + ko;
#pragma unroll
        for (int kb = 0; kb < 4; kb++) {
            Ai[mi][kb] = *(const short8*)(pi + kb * 32);
            Ap[mi][kb] = *(const short8*)(pp + kb * 32);
        }
    }
    float s1 = sigf(a1[0]), s2 = sigf(a2[0]);
    float* sc = out;
    float* si = out + (size_t)20480000;
    float* sp = out + (size_t)40960000;
    for (int nt = 0; nt < 4; nt++) {
        int col = n0 + nt * 16 + (l & 15);
        const u16* bi = ivbf + (size_t)col * 128 + ko;
        const u16* bp = pvbf + (size_t)col * 128 + ko;
        short8 Bi[4], Bp[4];
#pragma unroll
        for (int kb = 0; kb < 4; kb++) {
            Bi[kb] = *(const short8*)(bi + kb * 32);
            Bp[kb] = *(const short8*)(bp + kb * 32);
        }
#pragma unroll
        for (int mi = 0; mi < 4; mi++) {
            f32x4 ai = {0.f, 0.f, 0.f, 0.f}, ap = {0.f, 0.f, 0.f, 0.f};
#pragma unroll
            for (int kb = 0; kb < 4; kb++) {
                ai = mfma16(Ai[mi][kb], Bi[kb], ai);
                ap = mfma16(Ap[mi][kb], Bp[kb], ap);
            }
            int rowb = w * 64 + mi * 16 + (l >> 4) * 4;
#pragma unroll
            for (int q = 0; q < 4; q++) {
                size_t o = (size_t)(rowb + q) * 80000 + col;
                float vi = ai[q], vp = ap[q];
                si[o] = vi;
                sp[o] = vp;
                sc[o] = s1 * vi + s2 * vp;
            }
        }
    }
}

extern "C" void kernel_launch(void* const* d_in, const int* in_sizes, int n_in,
                              void* d_out, int out_size, void* d_ws, size_t ws_size,
                              hipStream_t stream) {
    (void)in_sizes; (void)n_in; (void)out_size; (void)ws_size;
    const int*   sess    = (const int*)d_in[0];
    const int*   lengths = (const int*)d_in[1];
    const float* tau     = (const float*)d_in[4];
    const int*   adj     = (const int*)d_in[5];
    const int*   anchors = (const int*)d_in[6];
    const float* emb     = (const float*)d_in[7];
    const float* W_ih    = (const float*)d_in[8];
    const float* W_hh    = (const float*)d_in[9];
    const float* b_ih    = (const float*)d_in[10];
    const float* b_hh    = (const float*)d_in[11];
    const float* W1      = (const float*)d_in[12];
    const float* b1      = (const float*)d_in[13];
    const float* W2      = (const float*)d_in[14];
    const float* b2      = (const float*)d_in[15];
    const float* a1      = (const float*)d_in[16];
    const float* a2      = (const float*)d_in[17];
    const float* ln1g = (const float*)d_in[18];
    const float* ln1b = (const float*)d_in[19];
    const float* ln2g = (const float*)d_in[20];
    const float* ln2b = (const float*)d_in[21];
    const float* ln3g = (const float*)d_in[22];
    const float* ln3b = (const float*)d_in[23];
    const float* ln4g = (const float*)d_in[24];
    const float* ln4b = (const float*)d_in[25];

    float* out = (float*)d_out;
    // d_out doubles as scratch; all scratch dead before k_scores overwrites it.
    u32*   o_xn = (u32*)out;                 // packed bf16 xn (5.12M u32)
    u32*   o_o1 = (u32*)(out + SLOT);        // packed bf16 hop-1 out
    float* o_gi = out + 2 * SLOT;            // gi_all (9.83M floats)

    u16* ws16   = (u16*)d_ws;        // ~41.3 MB
    u16* ivbf   = ws16;                      // 10,240,000
    u16* pvbf   = ws16 + 10240000;           // 10,240,000
    u16* wihbf  = ws16 + 20480000;           // 49,152
    u16* htbf   = ws16 + 20529152;           // 65,536
    u16* w1bf   = ws16 + 20594688;           // 16,384
    u16* w2bf   = ws16 + 20611072;           // 4,096
    u16* anchT  = ws16 + 20615168;           // 4,096

    k_cvtall<<<272, 256, 0, stream>>>(W_ih, W1, W2, wihbf, w1bf, w2bf);
    k_normb<<<20000, 256, 0, stream>>>(emb + 128, o_xn);
    k_routeb<<<5000, 256, 0, stream>>>(o_xn, adj, o_o1);
    k_route2lnb<<<5000, 256, 0, stream>>>(o_o1, emb + 128, adj, ln1g, ln1b, (u32*)ivbf);
    k_prep<<<1, 256, 0, stream>>>(anchors, ivbf, anchT);
    k_popm<<<1250, 256, 0, stream>>>(ivbf, w1bf, b1, w2bf, b2, tau, anchT,
                                     ln2g, ln2b, pvbf);
    k_gi<<<400, 256, 0, stream>>>(sess, ivbf, pvbf, wihbf, b_ih, o_gi);
    k_gru<<<512, 384, 0, stream>>>(o_gi, W_hh, b_hh, lengths, ln3g, ln3b, ln4g, ln4b,
                                   (u32*)htbf);
    k_scores<<<1250, 256, 0, stream>>>(htbf, ivbf, pvbf, a1, a2, out);
}